// Round 5
// baseline (798.292 us; speedup 1.0000x reference)
//
#include <hip/hip_runtime.h>
#include <hip/hip_bf16.h>
#include <math.h>

// Problem constants
static constexpr int Bc   = 32;
static constexpr int Nc   = 4096;
static constexpr int Dc   = 256;
static constexpr int NSc  = 8;
static constexpr int HIDc = 128;
static constexpr int ITERSc = 3;
#define EPSf 1e-8f
#define LN_EPSf 1e-5f

typedef __attribute__((ext_vector_type(8))) short bf16x8;
typedef __attribute__((ext_vector_type(8))) unsigned short u16x8;
typedef __attribute__((ext_vector_type(4))) float f32x4;

// Tw (transposed bf16 weights) element offsets
static constexpr int W1AT = 0;        // [256][128]  rel_w1 A-part^T
static constexpr int W1BT = 32768;    // [256][128]  rel_w1 B-part^T
static constexpr int W2T  = 65536;    // [128][256]  rel_w2^T
static constexpr int OW1T = 98304;    // [256][128]  obj_w1^T
static constexpr int OW2T = 131072;   // [128][256]  obj_w2^T
static constexpr int WHNT = 163840;   // [256][256]  w_hh n-part^T
static constexpr int TW_ELEMS = 229376;

__device__ __forceinline__ float bf2f(unsigned int u) {
  return __uint_as_float((u & 0xffffu) << 16);
}

__device__ __forceinline__ unsigned short f2bfu(float f) {
  unsigned int u = __float_as_uint(f);
  unsigned int r = (u + 0x7fffu + ((u >> 16) & 1u)) >> 16;
  return (unsigned short)r;
}

__device__ __forceinline__ void gl_lds16(const void* g, void* l) {
  __builtin_amdgcn_global_load_lds(
      (__attribute__((address_space(1))) void*)(g),
      (__attribute__((address_space(3))) void*)(l), 16, 0, 0);
}

__device__ __forceinline__ float block_sum(float v, float* tmp) {
  #pragma unroll
  for (int o = 32; o > 0; o >>= 1) v += __shfl_down(v, o, 64);
  int lane = threadIdx.x & 63, wid = threadIdx.x >> 6;
  __syncthreads();
  if (lane == 0) tmp[wid] = v;
  __syncthreads();
  return tmp[0] + tmp[1] + tmp[2] + tmp[3];
}

__device__ __forceinline__ float sigmf(float x) { return 1.f / (1.f + expf(-x)); }

// slots = mu + noise * exp(sigma)
__global__ __launch_bounds__(256) void k_init_slots(const float* __restrict__ noise,
                                                    const float* __restrict__ mu,
                                                    const float* __restrict__ sigma,
                                                    float* __restrict__ slots) {
  int idx = blockIdx.x * 256 + threadIdx.x;
  int d = idx & (Dc - 1);
  slots[idx] = mu[d] + noise[idx] * expf(sigma[d]);
}

// X = bf16 LN(inputs) row-major. 16 rows/block, grid 8192.
__global__ __launch_bounds__(256) void k_lnx(const float* __restrict__ inp,
                                             const float* __restrict__ lng,
                                             const float* __restrict__ lnb,
                                             unsigned short* __restrict__ X) {
  __shared__ float smu[16], srs[16];
  int t = threadIdx.x, lane = t & 63, w = t >> 6;
  size_t row0 = (size_t)blockIdx.x * 16;
  // stats: wave w -> rows w*4..w*4+3
  for (int rr = 0; rr < 4; rr++) {
    int row = w * 4 + rr;
    float4 v = *(const float4*)(inp + (row0 + row) * 256 + lane * 4);
    float s = v.x + v.y + v.z + v.w;
    float q = v.x * v.x + v.y * v.y + v.z * v.z + v.w * v.w;
    #pragma unroll
    for (int o = 32; o > 0; o >>= 1) { s += __shfl_down(s, o, 64); q += __shfl_down(q, o, 64); }
    if (lane == 0) {
      float mu = s * (1.0f / 256.0f);
      smu[row] = mu;
      srs[row] = rsqrtf(q * (1.0f / 256.0f) - mu * mu + LN_EPSf);
    }
  }
  __syncthreads();
  #pragma unroll
  for (int p = 0; p < 2; p++) {
    int idx = p * 256 + t;          // 512 chunks of 8
    int row = idx >> 5, ch = idx & 31;
    const float* src = inp + (row0 + row) * 256 + ch * 8;
    float mu = smu[row], rs = srs[row];
    float4 x0 = *(const float4*)(src);
    float4 x1 = *(const float4*)(src + 4);
    float4 g0 = *(const float4*)(lng + ch * 8);
    float4 g1 = *(const float4*)(lng + ch * 8 + 4);
    float4 b0 = *(const float4*)(lnb + ch * 8);
    float4 b1 = *(const float4*)(lnb + ch * 8 + 4);
    u16x8 pk;
    pk[0] = f2bfu((x0.x - mu) * rs * g0.x + b0.x);
    pk[1] = f2bfu((x0.y - mu) * rs * g0.y + b0.y);
    pk[2] = f2bfu((x0.z - mu) * rs * g0.z + b0.z);
    pk[3] = f2bfu((x0.w - mu) * rs * g0.w + b0.w);
    pk[4] = f2bfu((x1.x - mu) * rs * g1.x + b1.x);
    pk[5] = f2bfu((x1.y - mu) * rs * g1.y + b1.y);
    pk[6] = f2bfu((x1.z - mu) * rs * g1.z + b1.z);
    pk[7] = f2bfu((x1.w - mu) * rs * g1.w + b1.w);
    *(u16x8*)(X + (row0 + row) * 256 + ch * 8) = pk;
  }
}

// Wcat bf16 [768][768]: rows 0..511: [w_ih | w_hh]; rows 512..767: [w_ih_n | 0]
__global__ __launch_bounds__(256) void k_wprep(const float* __restrict__ w_ih,
                                               const float* __restrict__ w_hh,
                                               unsigned short* __restrict__ Wcat) {
  int idx = blockIdx.x * 256 + threadIdx.x;
  int o = idx / 768, c = idx - o * 768;
  float v;
  if (c < 512) v = w_ih[o * 512 + c];
  else v = (o < 512) ? w_hh[o * 256 + (c - 512)] : 0.f;
  Wcat[idx] = f2bfu(v);
}

// transposed bf16 weight pack (rel/obj/w_hh_n)
__global__ __launch_bounds__(256) void k_tprep(const float* __restrict__ rel_w1,
                                               const float* __restrict__ rel_w2,
                                               const float* __restrict__ obj_w1,
                                               const float* __restrict__ obj_w2,
                                               const float* __restrict__ w_hh,
                                               unsigned short* __restrict__ Tw) {
  int i = blockIdx.x * 256 + threadIdx.x;
  if (i >= TW_ELEMS) return;
  float v;
  if (i < W1BT) { int j = i - W1AT; int d = j >> 7, h = j & 127; v = rel_w1[h * 512 + d]; }
  else if (i < W2T)  { int j = i - W1BT; int d = j >> 7, h = j & 127; v = rel_w1[h * 512 + 256 + d]; }
  else if (i < OW1T) { int j = i - W2T;  int h = j >> 8, o = j & 255; v = rel_w2[o * 128 + h]; }
  else if (i < OW2T) { int j = i - OW1T; int d = j >> 7, h = j & 127; v = obj_w1[h * 256 + d]; }
  else if (i < WHNT) { int j = i - OW2T; int h = j >> 8, o = j & 255; v = obj_w2[o * 128 + h]; }
  else               { int j = i - WHNT; int d = j >> 8, o = j & 255; v = w_hh[(512 + o) * 256 + d]; }
  Tw[i] = f2bfu(v);
}

// MT[d][e] = M[e][d], M = Wk^T @ Wq  (qk_i = M ln_i). Also WvT[d][e] = Wv[e][d].
__global__ __launch_bounds__(256) void k_mprep(const float* __restrict__ Wk,
                                               const float* __restrict__ Wq,
                                               const float* __restrict__ Wv,
                                               float* __restrict__ MT,
                                               float* __restrict__ WvT) {
  int d = blockIdx.x, t = threadIdx.x;  // e = t
  float acc = 0.f;
  for (int c = 0; c < 256; c++) acc += Wk[c * 256 + t] * Wq[c * 256 + d];
  MT[d * 256 + t] = acc;
  WvT[d * 256 + t] = Wv[t * 256 + d];
}

// qk = M @ LN_s(slots) (bf16 out, rows 8..15 per batch zeroed); zero updraw + S.
__global__ __launch_bounds__(256) void k_qproj0(const float* __restrict__ slots,
                                                const float* __restrict__ MT,
                                                const float* __restrict__ g,
                                                const float* __restrict__ bb_,
                                                unsigned short* __restrict__ qkb,
                                                float* __restrict__ S,
                                                float* __restrict__ updraw) {
  __shared__ float xs[Dc];
  __shared__ float tmp[4];
  int t = threadIdx.x;
  int row = blockIdx.x;
  updraw[row * 256 + t] = 0.f;
  if (blockIdx.x == 0) S[t] = 0.f;
  float x = slots[row * Dc + t];
  float s = block_sum(x, tmp);
  float m = s * (1.0f / Dc);
  float dx = x - m;
  float s2 = block_sum(dx * dx, tmp);
  float rs = rsqrtf(s2 * (1.0f / Dc) + LN_EPSf);
  xs[t] = dx * rs * g[t] + bb_[t];
  __syncthreads();
  float acc = 0.f;
  for (int d = 0; d < 256; d++) acc += MT[d * 256 + t] * xs[d];
  int b = row >> 3, i = row & 7;
  qkb[(size_t)(b * 16 + i) * 256 + t] = f2bfu(acc);
  qkb[(size_t)(b * 16 + 8 + i) * 256 + t] = 0;
}

// Fused dots(MFMA)+softmax+EPS + PV partials. grid 32 b * 64 jc (64 tokens each)
__global__ __launch_bounds__(256) void k_attn(const unsigned short* __restrict__ qkb,
                                              const unsigned short* __restrict__ X,
                                              float* __restrict__ attn,
                                              float* __restrict__ S,
                                              float* __restrict__ updraw) {
  __shared__ unsigned short xs[64 * 256];  // 32 KB, xor-swizzled 16B chunks
  __shared__ float dots[16][68];
  __shared__ float at[8][64];
  __shared__ float parts[2][8][256];
  int t = threadIdx.x, lane = t & 63, w = t >> 6;
  int b = blockIdx.x >> 6, jc = blockIdx.x & 63;
  int j0 = jc * 64;
  // ---- stage X tile [64 tok][256 d] swizzled ----
  #pragma unroll
  for (int c = 0; c < 8; c++) {
    int slot = c * 256 + t;
    int tok = slot >> 5, sl = slot & 31;
    int gc = (sl & 24) | ((sl & 7) ^ (tok & 7));
    gl_lds16((const char*)X + (((size_t)(b * 4096 + j0 + tok)) * 256 + gc * 8) * 2,
             (char*)xs + (size_t)(c * 256 + w * 64) * 16);
  }
  // A-frag pointer (qk row m, L2-hot)
  int m = lane & 15, quad = lane >> 4;
  const unsigned short* qrow = qkb + (size_t)(b * 16 + m) * 256;
  __syncthreads();
  // ---- dots: wave w = token n-tile w ----
  f32x4 dacc = {0.f, 0.f, 0.f, 0.f};
  int tokb = w * 16 + m;
  #pragma unroll
  for (int ks = 0; ks < 8; ks++) {
    bf16x8 afr = *(const bf16x8*)(qrow + ks * 32 + quad * 8);
    int kchunk = ks * 4 + quad;
    int slot = (kchunk & 24) | ((kchunk & 7) ^ (tokb & 7));
    bf16x8 bfr = *(const bf16x8*)((const char*)xs + (size_t)tokb * 512 + slot * 16);
    dacc = __builtin_amdgcn_mfma_f32_16x16x32_bf16(afr, bfr, dacc, 0, 0, 0);
  }
  #pragma unroll
  for (int r = 0; r < 4; r++) dots[quad * 4 + r][tokb] = dacc[r];
  __syncthreads();
  // ---- softmax over 8 slots per token (threads 0..63) ----
  if (t < 64) {
    float a[8], mx = -1e30f;
    #pragma unroll
    for (int i = 0; i < 8; i++) { a[i] = dots[i][t] * 0.0625f; mx = fmaxf(mx, a[i]); }
    float sum = 0.f;
    #pragma unroll
    for (int i = 0; i < 8; i++) { a[i] = expf(a[i] - mx); sum += a[i]; }
    float inv = 1.f / sum;
    float* ab = attn + (size_t)b * NSc * Nc;
    #pragma unroll
    for (int i = 0; i < 8; i++) {
      float v = a[i] * inv + EPSf;
      a[i] = v;
      at[i][t] = v;
      ab[i * Nc + j0 + t] = v;
    }
    #pragma unroll
    for (int i = 0; i < 8; i++) {
      float s = a[i];
      #pragma unroll
      for (int o = 32; o > 0; o >>= 1) s += __shfl_down(s, o, 64);
      if (lane == 0) atomicAdd(&S[b * NSc + i], s);
    }
  }
  __syncthreads();
  // ---- PV: thread = (d-pair dg, token-half h) ----
  int dg = t & 127, h = t >> 7;
  float acc[8][2];
  #pragma unroll
  for (int i = 0; i < 8; i++) { acc[i][0] = 0.f; acc[i][1] = 0.f; }
  int kchunk = dg >> 2;
  for (int jj = 0; jj < 32; jj++) {
    int tok = h * 32 + jj;
    int slot = (kchunk & 24) | ((kchunk & 7) ^ (tok & 7));
    unsigned int xv = *(const unsigned int*)((const char*)xs + (size_t)tok * 512 + slot * 16 + (dg & 3) * 4);
    float x0 = bf2f(xv), x1 = bf2f(xv >> 16);
    #pragma unroll
    for (int i = 0; i < 8; i++) {
      float av = at[i][tok];
      acc[i][0] += av * x0;
      acc[i][1] += av * x1;
    }
  }
  #pragma unroll
  for (int i = 0; i < 8; i++)
    *(float2*)&parts[h][i][dg * 2] = make_float2(acc[i][0], acc[i][1]);
  __syncthreads();
  for (int i = 0; i < 8; i++) {
    float val = parts[0][i][t] + parts[1][i][t];
    atomicAdd(&updraw[(size_t)(b * NSc + i) * 256 + t], val);
  }
}

// Relational MLP + Wv-transform of updates + X build. grid 64
__global__ __launch_bounds__(256) void k_slot_a(const float* __restrict__ slots,
                                                const float* __restrict__ updraw,
                                                const float* __restrict__ S,
                                                const unsigned short* __restrict__ Tw,
                                                const float* __restrict__ WvT,
                                                const float* __restrict__ b1,
                                                const float* __restrict__ b2,
                                                unsigned short* __restrict__ Xb) {
  __shared__ float sp[NSc][256];
  __shared__ float un[4][256];
  __shared__ float xpart[2][12][128];
  __shared__ float xabl[12][128];
  __shared__ float hs[4][128];
  int t = threadIdx.x;
  int b = blockIdx.x >> 1, half = blockIdx.x & 1;
  int i0 = half * 4;
  for (int x = t; x < NSc * 256; x += 256) sp[x >> 8][x & 255] = slots[b * NSc * 256 + x];
  for (int r = 0; r < 4; r++) {
    int grow = b * NSc + i0 + r;
    un[r][t] = updraw[(size_t)grow * 256 + t] / S[grow];
  }
  __syncthreads();
  // upd = Wv @ u_n ; slots part of X
  {
    float av[4] = {0.f, 0.f, 0.f, 0.f};
    for (int d = 0; d < 256; d++) {
      float wv = WvT[d * 256 + t];
      #pragma unroll
      for (int r = 0; r < 4; r++) av[r] += wv * un[r][d];
    }
    for (int r = 0; r < 4; r++) {
      int grow = b * NSc + i0 + r;
      Xb[(size_t)grow * 768 + t] = f2bfu(av[r]);
      Xb[(size_t)grow * 768 + 512 + t] = f2bfu(sp[i0 + r][t]);
    }
  }
  int h = t & 127, dh = t >> 7;
  {
    const unsigned short* wa = Tw + W1AT;
    const unsigned short* wb = Tw + W1BT;
    float accb[8] = {0, 0, 0, 0, 0, 0, 0, 0};
    float acca[4] = {0, 0, 0, 0};
    for (int dd = 0; dd < 128; dd++) {
      int d = dh * 128 + dd;
      float wbv = bf2f(wb[d * 128 + h]);
      float wav = bf2f(wa[d * 128 + h]);
      #pragma unroll
      for (int jj = 0; jj < 8; jj++) accb[jj] += wbv * sp[jj][d];
      #pragma unroll
      for (int r = 0; r < 4; r++) acca[r] += wav * sp[i0 + r][d];
    }
    #pragma unroll
    for (int jj = 0; jj < 8; jj++) xpart[dh][jj][h] = accb[jj];
    #pragma unroll
    for (int r = 0; r < 4; r++) xpart[dh][8 + r][h] = acca[r];
  }
  __syncthreads();
  {
    int g = t >> 7;
    for (int jj = g * 6; jj < g * 6 + 6; jj++)
      xabl[jj][h] = xpart[0][jj][h] + xpart[1][jj][h];
  }
  __syncthreads();
  {
    float bv = b1[h];
    int ig = t >> 7;
    #pragma unroll
    for (int ii = 0; ii < 2; ii++) {
      int il = ig * 2 + ii;
      int ibatch = i0 + il;
      float av = xabl[8 + il][h];
      float s = 0.f;
      #pragma unroll
      for (int jj = 0; jj < NSc; jj++) {
        if (jj == ibatch) continue;
        s += fmaxf(av + xabl[jj][h] + bv, 0.f);
      }
      hs[il][h] = s;
    }
  }
  __syncthreads();
  {
    const unsigned short* w2 = Tw + W2T;
    float am[4] = {0, 0, 0, 0};
    for (int hh = 0; hh < 128; hh++) {
      float wv = bf2f(w2[hh * 256 + t]);
      #pragma unroll
      for (int r = 0; r < 4; r++) am[r] += wv * hs[r][hh];
    }
    float bv2 = b2[t];
    for (int r = 0; r < 4; r++) {
      float rel = am[r] * (1.0f / 7.0f) + bv2;
      Xb[(size_t)(b * NSc + i0 + r) * 768 + 256 + t] = f2bfu(rel);
    }
  }
}

// Gates GEMM: Y[256][768] = Xb @ Wcat^T (bf16, fp32 acc). grid 48
__global__ __launch_bounds__(256) void k_gates(const unsigned short* __restrict__ Xb,
                                               const unsigned short* __restrict__ Wcat,
                                               unsigned short* __restrict__ Yb) {
  __shared__ unsigned short Als[64 * 64];
  __shared__ unsigned short Bls[64 * 64];
  int tid = threadIdx.x;
  int lane = tid & 63, w = tid >> 6;
  int idx16 = lane & 15, quad = lane >> 4;
  int m0 = (blockIdx.x / 12) * 64;
  int n0 = (blockIdx.x % 12) * 64;
  int wm = w & 1, wn = w >> 1;
  f32x4 acc[2][2];
  #pragma unroll
  for (int i = 0; i < 2; i++)
    #pragma unroll
    for (int j = 0; j < 2; j++) acc[i][j] = (f32x4){0.f, 0.f, 0.f, 0.f};

  for (int kt = 0; kt < 12; kt++) {
    int k0 = kt * 64;
    #pragma unroll
    for (int c = 0; c < 2; c++) {
      int idx = (w * 2 + c) * 64 + lane;
      int row = idx >> 3, lc = idx & 7;
      int gc = lc ^ (row & 7);
      gl_lds16((const char*)Xb + (size_t)(m0 + row) * 1536 + k0 * 2 + gc * 16,
               (char*)Als + (size_t)(w * 2 + c) * 1024);
      gl_lds16((const char*)Wcat + (size_t)(n0 + row) * 1536 + k0 * 2 + gc * 16,
               (char*)Bls + (size_t)(w * 2 + c) * 1024);
    }
    __syncthreads();
    #pragma unroll
    for (int ks = 0; ks < 2; ks++) {
      bf16x8 af[2], bfr[2];
      int kchunk = ks * 4 + quad;
      #pragma unroll
      for (int mt = 0; mt < 2; mt++) {
        int row = wm * 32 + mt * 16 + idx16;
        af[mt] = *(const bf16x8*)((const char*)Als + (size_t)(row * 8 + (kchunk ^ (row & 7))) * 16);
      }
      #pragma unroll
      for (int nt = 0; nt < 2; nt++) {
        int row = wn * 32 + nt * 16 + idx16;
        bfr[nt] = *(const bf16x8*)((const char*)Bls + (size_t)(row * 8 + (kchunk ^ (row & 7))) * 16);
      }
      #pragma unroll
      for (int mt = 0; mt < 2; mt++)
        #pragma unroll
        for (int nt = 0; nt < 2; nt++)
          acc[mt][nt] = __builtin_amdgcn_mfma_f32_16x16x32_bf16(af[mt], bfr[nt], acc[mt][nt], 0, 0, 0);
    }
    __syncthreads();
  }
  #pragma unroll
  for (int mt = 0; mt < 2; mt++) {
    #pragma unroll
    for (int nt = 0; nt < 2; nt++) {
      int gm = m0 + wm * 32 + mt * 16 + quad * 4;
      int col = n0 + wn * 32 + nt * 16 + idx16;
      #pragma unroll
      for (int r = 0; r < 4; r++)
        Yb[(size_t)(gm + r) * 768 + col] = f2bfu(acc[mt][nt][r]);
    }
  }
}

// GRU elementwise + LN + FF + residual + next-iter qk. grid 64 (4 rows/block)
__global__ __launch_bounds__(256) void k_slot_c(const unsigned short* __restrict__ Yb,
                                                const unsigned short* __restrict__ Tw,
                                                const float* __restrict__ MT,
                                                const float* __restrict__ b_ih,
                                                const float* __restrict__ b_hh,
                                                float* __restrict__ slots,
                                                const float* __restrict__ ob1,
                                                const float* __restrict__ ob2,
                                                const float* __restrict__ lng,
                                                const float* __restrict__ lnb,
                                                const float* __restrict__ lsg,
                                                const float* __restrict__ lsb,
                                                unsigned short* __restrict__ qkb,
                                                float* __restrict__ updraw,
                                                float* __restrict__ S,
                                                float* __restrict__ outf,
                                                int wfinal) {
  __shared__ float sp4[4][256];
  __shared__ float ffl[4][256];
  __shared__ float h1p[2][4][128];
  __shared__ float h1l[4][128];
  __shared__ float xs2[4][256];
  int t = threadIdx.x;
  int g0 = blockIdx.x * 4;
  for (int x = t; x < 1024; x += 256) sp4[x >> 8][x & 255] = slots[(size_t)g0 * 256 + x];
  __syncthreads();
  float hn[4] = {0, 0, 0, 0};
  {
    const unsigned short* wh = Tw + WHNT;
    for (int d = 0; d < 256; d++) {
      float wv = bf2f(wh[d * 256 + t]);
      #pragma unroll
      for (int r = 0; r < 4; r++) hn[r] += wv * sp4[r][d];
    }
  }
  float bir = b_ih[t], bhr = b_hh[t];
  float biz = b_ih[256 + t], bhz = b_hh[256 + t];
  float bin_ = b_ih[512 + t], bhn = b_hh[512 + t];
  float snew[4];
  #pragma unroll
  for (int r = 0; r < 4; r++) {
    size_t yoff = (size_t)(g0 + r) * 768;
    float yr = bf2f((unsigned int)Yb[yoff + t]);
    float yz = bf2f((unsigned int)Yb[yoff + 256 + t]);
    float yx = bf2f((unsigned int)Yb[yoff + 512 + t]);
    float rg = sigmf(yr + bir + bhr);
    float zg = sigmf(yz + biz + bhz);
    float ng = tanhf(yx + bin_ + rg * (hn[r] + bhn));
    snew[r] = (1.f - zg) * ng + zg * sp4[r][t];
    ffl[r][t] = snew[r];
  }
  __syncthreads();
  // wave-per-row LN_ff
  {
    int wv = t >> 6, lane = t & 63;
    float4 v = *(const float4*)&ffl[wv][lane * 4];
    float s = v.x + v.y + v.z + v.w;
    float q = v.x * v.x + v.y * v.y + v.z * v.z + v.w * v.w;
    #pragma unroll
    for (int o = 32; o > 0; o >>= 1) { s += __shfl_down(s, o, 64); q += __shfl_down(q, o, 64); }
    s = __shfl(s, 0, 64); q = __shfl(q, 0, 64);
    float mu = s * (1.0f / 256.0f);
    float rs = rsqrtf(q * (1.0f / 256.0f) - mu * mu + LN_EPSf);
    float4 g4 = *(const float4*)&lng[lane * 4];
    float4 b4 = *(const float4*)&lnb[lane * 4];
    float4 o4;
    o4.x = (v.x - mu) * rs * g4.x + b4.x;
    o4.y = (v.y - mu) * rs * g4.y + b4.y;
    o4.z = (v.z - mu) * rs * g4.z + b4.z;
    o4.w = (v.w - mu) * rs * g4.w + b4.w;
    *(float4*)&ffl[wv][lane * 4] = o4;
  }
  __syncthreads();
  {
    const unsigned short* w1 = Tw + OW1T;
    int h = t & 127, dh = t >> 7;
    float a1[4] = {0, 0, 0, 0};
    for (int dd = 0; dd < 128; dd++) {
      int d = dh * 128 + dd;
      float wv = bf2f(w1[d * 128 + h]);
      #pragma unroll
      for (int r = 0; r < 4; r++) a1[r] += wv * ffl[r][d];
    }
    #pragma unroll
    for (int r = 0; r < 4; r++) h1p[dh][r][h] = a1[r];
  }
  __syncthreads();
  {
    int h = t & 127, g = t >> 7;
    float bo = ob1[h];
    #pragma unroll
    for (int rr = 0; rr < 2; rr++) {
      int r = g * 2 + rr;
      h1l[r][h] = fmaxf(h1p[0][r][h] + h1p[1][r][h] + bo, 0.f);
    }
  }
  __syncthreads();
  float res[4];
  {
    const unsigned short* w2 = Tw + OW2T;
    float ao[4] = {0, 0, 0, 0};
    for (int hh = 0; hh < 128; hh++) {
      float wv = bf2f(w2[hh * 256 + t]);
      #pragma unroll
      for (int r = 0; r < 4; r++) ao[r] += wv * h1l[r][hh];
    }
    float bo2 = ob2[t];
    #pragma unroll
    for (int r = 0; r < 4; r++) res[r] = snew[r] + ao[r] + bo2;
  }
  #pragma unroll
  for (int r = 0; r < 4; r++) {
    slots[(size_t)(g0 + r) * 256 + t] = res[r];
    if (wfinal) outf[(size_t)(g0 + r) * 256 + t] = res[r];
    xs2[r][t] = res[r];
  }
  __syncthreads();
  // wave-per-row LN_s
  {
    int wv = t >> 6, lane = t & 63;
    float4 v = *(const float4*)&xs2[wv][lane * 4];
    float s = v.x + v.y + v.z + v.w;
    float q = v.x * v.x + v.y * v.y + v.z * v.z + v.w * v.w;
    #pragma unroll
    for (int o = 32; o > 0; o >>= 1) { s += __shfl_down(s, o, 64); q += __shfl_down(q, o, 64); }
    s = __shfl(s, 0, 64); q = __shfl(q, 0, 64);
    float mu = s * (1.0f / 256.0f);
    float rs = rsqrtf(q * (1.0f / 256.0f) - mu * mu + LN_EPSf);
    float4 g4 = *(const float4*)&lsg[lane * 4];
    float4 b4 = *(const float4*)&lsb[lane * 4];
    float4 o4;
    o4.x = (v.x - mu) * rs * g4.x + b4.x;
    o4.y = (v.y - mu) * rs * g4.y + b4.y;
    o4.z = (v.z - mu) * rs * g4.z + b4.z;
    o4.w = (v.w - mu) * rs * g4.w + b4.w;
    *(float4*)&xs2[wv][lane * 4] = o4;
  }
  __syncthreads();
  // qk = M @ LN_s(res)
  {
    float aq[4] = {0, 0, 0, 0};
    for (int d = 0; d < 256; d++) {
      float wv = MT[d * 256 + t];
      #pragma unroll
      for (int r = 0; r < 4; r++) aq[r] += wv * xs2[r][d];
    }
    #pragma unroll
    for (int r = 0; r < 4; r++) {
      int grow = g0 + r;
      int b = grow >> 3, i = grow & 7;
      qkb[(size_t)(b * 16 + i) * 256 + t] = f2bfu(aq[r]);
      qkb[(size_t)(b * 16 + 8 + i) * 256 + t] = 0;
    }
  }
  #pragma unroll
  for (int r = 0; r < 4; r++) updraw[(size_t)(g0 + r) * 256 + t] = 0.f;
  if (t < 4) S[g0 + t] = 0.f;
}

extern "C" void kernel_launch(void* const* d_in, const int* in_sizes, int n_in,
                              void* d_out, int out_size, void* d_ws, size_t ws_size,
                              hipStream_t stream) {
  const float* inputs      = (const float*)d_in[0];
  const float* slot_noise  = (const float*)d_in[1];
  const float* slots_mu    = (const float*)d_in[2];
  const float* slots_sigma = (const float*)d_in[3];
  const float* Wq          = (const float*)d_in[4];
  const float* Wk          = (const float*)d_in[5];
  const float* Wv          = (const float*)d_in[6];
  const float* gru_w_ih    = (const float*)d_in[7];
  const float* gru_w_hh    = (const float*)d_in[8];
  const float* gru_b_ih    = (const float*)d_in[9];
  const float* gru_b_hh    = (const float*)d_in[10];
  const float* obj_w1      = (const float*)d_in[11];
  const float* obj_b1      = (const float*)d_in[12];
  const float* obj_w2      = (const float*)d_in[13];
  const float* obj_b2      = (const float*)d_in[14];
  const float* rel_w1      = (const float*)d_in[15];
  const float* rel_b1      = (const float*)d_in[16];
  const float* rel_w2      = (const float*)d_in[17];
  const float* rel_b2      = (const float*)d_in[18];
  const float* ln_in_g     = (const float*)d_in[19];
  const float* ln_in_b     = (const float*)d_in[20];
  const float* ln_s_g      = (const float*)d_in[21];
  const float* ln_s_b      = (const float*)d_in[22];
  const float* ln_ff_g     = (const float*)d_in[23];
  const float* ln_ff_b     = (const float*)d_in[24];

  // workspace layout (bytes), total 70,976,512:
  //   X bf16    : 0          (+67,108,864)   LN(inputs), the ONLY big buffer
  //   slots f32 : 67,108,864 (+262,144)
  //   updraw f32: 67,371,008 (+262,144)
  //   Sbuf f32  : 67,633,152 (+1,024)
  //   Wcat bf16 : 67,634,176 (+1,179,648)
  //   Tw bf16   : 68,813,824 (+589,824)
  //   Xbuf bf16 : 69,403,648 (+393,216)
  //   Ybuf bf16 : 69,796,864 (+393,216)
  //   qkb bf16  : 70,190,080 (+262,144)   [32][16][256], rows 8..15 zeroed
  //   MT f32    : 70,452,224 (+262,144)   (Wk^T Wq)^T
  //   WvT f32   : 70,714,368 (+262,144)
  char* w = (char*)d_ws;
  unsigned short* X    = (unsigned short*)(w);
  float* slots  = (float*)(w + (size_t)67108864);
  float* updraw = (float*)(w + (size_t)67371008);
  float* Sbuf   = (float*)(w + (size_t)67633152);
  unsigned short* Wcat = (unsigned short*)(w + (size_t)67634176);
  unsigned short* Tw   = (unsigned short*)(w + (size_t)68813824);
  unsigned short* Xbuf = (unsigned short*)(w + (size_t)69403648);
  unsigned short* Ybuf = (unsigned short*)(w + (size_t)69796864);
  unsigned short* qkb  = (unsigned short*)(w + (size_t)70190080);
  float* MT  = (float*)(w + (size_t)70452224);
  float* WvT = (float*)(w + (size_t)70714368);

  float* out = (float*)d_out;
  float* attn_base = out + (size_t)Bc * NSc * Dc;

  k_init_slots<<<Bc * NSc * Dc / 256, 256, 0, stream>>>(slot_noise, slots_mu, slots_sigma, slots);
  k_lnx<<<Bc * Nc / 16, 256, 0, stream>>>(inputs, ln_in_g, ln_in_b, X);
  k_wprep<<<768 * 768 / 256, 256, 0, stream>>>(gru_w_ih, gru_w_hh, Wcat);
  k_tprep<<<(TW_ELEMS + 255) / 256, 256, 0, stream>>>(rel_w1, rel_w2, obj_w1, obj_w2, gru_w_hh, Tw);
  k_mprep<<<256, 256, 0, stream>>>(Wk, Wq, Wv, MT, WvT);
  k_qproj0<<<Bc * NSc, 256, 0, stream>>>(slots, MT, ln_s_g, ln_s_b, qkb, Sbuf, updraw);

  for (int it = 0; it < ITERSc; it++) {
    float* attn = attn_base + (size_t)it * Bc * NSc * Nc;
    k_attn<<<Bc * 64, 256, 0, stream>>>(qkb, X, attn, Sbuf, updraw);
    k_slot_a<<<Bc * 2, 256, 0, stream>>>(slots, updraw, Sbuf, Tw, WvT, rel_b1, rel_b2, Xbuf);
    k_gates<<<4 * 12, 256, 0, stream>>>(Xbuf, Wcat, Ybuf);
    k_slot_c<<<64, 256, 0, stream>>>(Ybuf, Tw, MT, gru_b_ih, gru_b_hh, slots,
                                     obj_b1, obj_b2, ln_ff_g, ln_ff_b, ln_s_g, ln_s_b,
                                     qkb, updraw, Sbuf,
                                     out, it == ITERSc - 1 ? 1 : 0);
  }
}

// Round 6
// 665.907 us; speedup vs baseline: 1.1988x; 1.1988x over previous
//
#include <hip/hip_runtime.h>
#include <hip/hip_bf16.h>
#include <math.h>

// Problem constants
static constexpr int Bc   = 32;
static constexpr int Nc   = 4096;
static constexpr int Dc   = 256;
static constexpr int NSc  = 8;
static constexpr int HIDc = 128;
static constexpr int ITERSc = 3;
#define EPSf 1e-8f
#define LN_EPSf 1e-5f

typedef __attribute__((ext_vector_type(8))) short bf16x8;
typedef __attribute__((ext_vector_type(8))) unsigned short u16x8;
typedef __attribute__((ext_vector_type(4))) float f32x4;

// Tw (transposed bf16 weights) element offsets
static constexpr int W1AT = 0;        // [256][128]  rel_w1 A-part^T
static constexpr int W1BT = 32768;    // [256][128]  rel_w1 B-part^T
static constexpr int W2T  = 65536;    // [128][256]  rel_w2^T
static constexpr int OW1T = 98304;    // [256][128]  obj_w1^T
static constexpr int OW2T = 131072;   // [128][256]  obj_w2^T
static constexpr int WHNT = 163840;   // [256][256]  w_hh n-part^T
static constexpr int TW_ELEMS = 229376;

__device__ __forceinline__ float bf2f(unsigned int u) {
  return __uint_as_float((u & 0xffffu) << 16);
}

__device__ __forceinline__ unsigned short f2bfu(float f) {
  unsigned int u = __float_as_uint(f);
  unsigned int r = (u + 0x7fffu + ((u >> 16) & 1u)) >> 16;
  return (unsigned short)r;
}

__device__ __forceinline__ void gl_lds16(const void* g, void* l) {
  __builtin_amdgcn_global_load_lds(
      (__attribute__((address_space(1))) void*)(g),
      (__attribute__((address_space(3))) void*)(l), 16, 0, 0);
}

__device__ __forceinline__ float block_sum(float v, float* tmp) {
  #pragma unroll
  for (int o = 32; o > 0; o >>= 1) v += __shfl_down(v, o, 64);
  int lane = threadIdx.x & 63, wid = threadIdx.x >> 6;
  __syncthreads();
  if (lane == 0) tmp[wid] = v;
  __syncthreads();
  return tmp[0] + tmp[1] + tmp[2] + tmp[3];
}

__device__ __forceinline__ float sigmf(float x) { return 1.f / (1.f + expf(-x)); }

// slots = mu + noise * exp(sigma)
__global__ __launch_bounds__(256) void k_init_slots(const float* __restrict__ noise,
                                                    const float* __restrict__ mu,
                                                    const float* __restrict__ sigma,
                                                    float* __restrict__ slots) {
  int idx = blockIdx.x * 256 + threadIdx.x;
  int d = idx & (Dc - 1);
  slots[idx] = mu[d] + noise[idx] * expf(sigma[d]);
}

// X = bf16 LN(inputs) row-major AND XT = column-major (per batch). 64 rows/block.
__global__ __launch_bounds__(256) void k_lnx(const float* __restrict__ inp,
                                             const float* __restrict__ lng,
                                             const float* __restrict__ lnb,
                                             unsigned short* __restrict__ X,
                                             unsigned short* __restrict__ XT) {
  __shared__ float smu[64], srs[64];
  __shared__ unsigned short xt[64][264];   // row stride 264 (528 B = 33*16, aligned)
  int t = threadIdx.x, lane = t & 63, w = t >> 6;
  int b = blockIdx.x >> 6;
  int tok0 = (blockIdx.x & 63) * 64;
  size_t row0 = (size_t)b * 4096 + tok0;
  // stats: wave w -> rows w*16..w*16+15
  for (int rr = 0; rr < 16; rr++) {
    int row = w * 16 + rr;
    float4 v = *(const float4*)(inp + (row0 + row) * 256 + lane * 4);
    float s = v.x + v.y + v.z + v.w;
    float q = v.x * v.x + v.y * v.y + v.z * v.z + v.w * v.w;
    #pragma unroll
    for (int o = 32; o > 0; o >>= 1) { s += __shfl_down(s, o, 64); q += __shfl_down(q, o, 64); }
    if (lane == 0) {
      float mu = s * (1.0f / 256.0f);
      smu[row] = mu;
      srs[row] = rsqrtf(q * (1.0f / 256.0f) - mu * mu + LN_EPSf);
    }
  }
  __syncthreads();
  #pragma unroll
  for (int p = 0; p < 8; p++) {
    int idx = p * 256 + t;          // 2048 chunks of 8 elems (64 rows x 32 chunks)
    int row = idx >> 5, ch = idx & 31;
    const float* src = inp + (row0 + row) * 256 + ch * 8;
    float mu = smu[row], rs = srs[row];
    float4 x0 = *(const float4*)(src);
    float4 x1 = *(const float4*)(src + 4);
    float4 g0 = *(const float4*)(lng + ch * 8);
    float4 g1 = *(const float4*)(lng + ch * 8 + 4);
    float4 b0 = *(const float4*)(lnb + ch * 8);
    float4 b1 = *(const float4*)(lnb + ch * 8 + 4);
    u16x8 pk;
    pk[0] = f2bfu((x0.x - mu) * rs * g0.x + b0.x);
    pk[1] = f2bfu((x0.y - mu) * rs * g0.y + b0.y);
    pk[2] = f2bfu((x0.z - mu) * rs * g0.z + b0.z);
    pk[3] = f2bfu((x0.w - mu) * rs * g0.w + b0.w);
    pk[4] = f2bfu((x1.x - mu) * rs * g1.x + b1.x);
    pk[5] = f2bfu((x1.y - mu) * rs * g1.y + b1.y);
    pk[6] = f2bfu((x1.z - mu) * rs * g1.z + b1.z);
    pk[7] = f2bfu((x1.w - mu) * rs * g1.w + b1.w);
    *(u16x8*)(X + (row0 + row) * 256 + ch * 8) = pk;
    *(u16x8*)&xt[row][ch * 8] = pk;
  }
  __syncthreads();
  // XT write: thread t = d, writes 64 toks (128 B contiguous)
  {
    unsigned short* dst = XT + ((size_t)(b * 256 + t)) * 4096 + tok0;
    #pragma unroll
    for (int g = 0; g < 8; g++) {
      u16x8 o;
      #pragma unroll
      for (int u = 0; u < 8; u++) o[u] = xt[g * 8 + u][t];
      *(u16x8*)(dst + g * 8) = o;
    }
  }
}

// Wcat1 bf16 [512][768]: row o = [w_ih_rz[o] | w_hh_rz[o]]
// Wcat2 bf16 [256][512]: row o = w_ih_n[o]
__global__ __launch_bounds__(256) void k_wprep(const float* __restrict__ w_ih,
                                               const float* __restrict__ w_hh,
                                               unsigned short* __restrict__ Wcat1,
                                               unsigned short* __restrict__ Wcat2) {
  int idx = blockIdx.x * 256 + threadIdx.x;  // 0..524287
  if (idx < 512 * 768) {
    int o = idx / 768, c = idx - o * 768;
    float v = (c < 512) ? w_ih[o * 512 + c] : w_hh[o * 256 + (c - 512)];
    Wcat1[idx] = f2bfu(v);
  } else {
    int j = idx - 512 * 768;
    int o = j >> 9, c = j & 511;
    Wcat2[j] = f2bfu(w_ih[(512 + o) * 512 + c]);
  }
}

// transposed bf16 weight pack (rel/obj/w_hh_n)
__global__ __launch_bounds__(256) void k_tprep(const float* __restrict__ rel_w1,
                                               const float* __restrict__ rel_w2,
                                               const float* __restrict__ obj_w1,
                                               const float* __restrict__ obj_w2,
                                               const float* __restrict__ w_hh,
                                               unsigned short* __restrict__ Tw) {
  int i = blockIdx.x * 256 + threadIdx.x;
  if (i >= TW_ELEMS) return;
  float v;
  if (i < W1BT) { int j = i - W1AT; int d = j >> 7, h = j & 127; v = rel_w1[h * 512 + d]; }
  else if (i < W2T)  { int j = i - W1BT; int d = j >> 7, h = j & 127; v = rel_w1[h * 512 + 256 + d]; }
  else if (i < OW1T) { int j = i - W2T;  int h = j >> 8, o = j & 255; v = rel_w2[o * 128 + h]; }
  else if (i < OW2T) { int j = i - OW1T; int d = j >> 7, h = j & 127; v = obj_w1[h * 256 + d]; }
  else if (i < WHNT) { int j = i - OW2T; int h = j >> 8, o = j & 255; v = obj_w2[o * 128 + h]; }
  else               { int j = i - WHNT; int d = j >> 8, o = j & 255; v = w_hh[(512 + o) * 256 + d]; }
  Tw[i] = f2bfu(v);
}

// MTb[d][e] = bf16((Wk^T Wq)[e][d]); WvTb[d][e] = bf16(Wv[e][d])
__global__ __launch_bounds__(256) void k_mprep(const float* __restrict__ Wk,
                                               const float* __restrict__ Wq,
                                               const float* __restrict__ Wv,
                                               unsigned short* __restrict__ MTb,
                                               unsigned short* __restrict__ WvTb) {
  int d = blockIdx.x, t = threadIdx.x;  // e = t
  float acc = 0.f;
  for (int c = 0; c < 256; c++) acc += Wk[c * 256 + t] * Wq[c * 256 + d];
  MTb[d * 256 + t] = f2bfu(acc);
  WvTb[d * 256 + t] = f2bfu(Wv[t * 256 + d]);
}

// qk = M @ LN_s(slots) (bf16, compact [256][256]); zero updraw + S.
__global__ __launch_bounds__(256) void k_qproj0(const float* __restrict__ slots,
                                                const unsigned short* __restrict__ MTb,
                                                const float* __restrict__ g,
                                                const float* __restrict__ bb_,
                                                unsigned short* __restrict__ qkb,
                                                float* __restrict__ S,
                                                float* __restrict__ updraw) {
  __shared__ float xs[Dc];
  __shared__ float tmp[4];
  int t = threadIdx.x;
  int row = blockIdx.x;
  updraw[row * 256 + t] = 0.f;
  if (blockIdx.x == 0) S[t] = 0.f;
  float x = slots[row * Dc + t];
  float s = block_sum(x, tmp);
  float m = s * (1.0f / Dc);
  float dx = x - m;
  float s2 = block_sum(dx * dx, tmp);
  float rs = rsqrtf(s2 * (1.0f / Dc) + LN_EPSf);
  xs[t] = dx * rs * g[t] + bb_[t];
  __syncthreads();
  float acc = 0.f;
  for (int d = 0; d < 256; d++) acc += bf2f(MTb[d * 256 + t]) * xs[d];
  qkb[(size_t)row * 256 + t] = f2bfu(acc);
}

// All-MFMA fused dots+softmax+EPS+PV. grid 32 b * 8 chunks (512 toks); wave = 128 toks.
__global__ __launch_bounds__(256) void k_attn(const unsigned short* __restrict__ qkb,
                                              const unsigned short* __restrict__ X,
                                              const unsigned short* __restrict__ XT,
                                              float* __restrict__ attn,
                                              float* __restrict__ S,
                                              float* __restrict__ updraw) {
  __shared__ unsigned short at_bf[4][16][136];  // per-wave attn (bf16), rows 8..15 zero
  __shared__ float updw[4][8][256];
  int t = threadIdx.x, lane = t & 63, w = t >> 6;
  int b = blockIdx.x >> 3, chunk = blockIdx.x & 7;
  int n = lane & 15, quad = lane >> 4;
  int tokbase = chunk * 512 + w * 128;
  // zero pad rows 8..15 of own wave's at_bf (contiguous 8*136 ushort = 544 words)
  {
    unsigned int* z = (unsigned int*)&at_bf[w][8][0];
    for (int i = lane; i < 544 / 2 * 2 / 2; i += 64) z[i] = 0;  // 544 uints? no:
  }
  // (rows 8..15 = 8*136 = 1088 ushort = 544 uint words)
  {
    unsigned int* z = (unsigned int*)&at_bf[w][8][0];
    for (int i = lane; i < 544; i += 64) z[i] = 0u;
  }
  const unsigned short* qrow = qkb + ((size_t)(b * 8 + (n & 7))) * 256 + quad * 8;
  const unsigned short* xbase = X + ((size_t)(b * 4096 + tokbase + n)) * 256 + quad * 8;
  bf16x8 zz;
  #pragma unroll
  for (int u = 0; u < 8; u++) zz[u] = 0;
  float sacc[4] = {0.f, 0.f, 0.f, 0.f};
  for (int tt = 0; tt < 8; tt++) {
    f32x4 dacc = {0.f, 0.f, 0.f, 0.f};
    const unsigned short* xrow = xbase + (size_t)(tt * 16) * 256;
    #pragma unroll
    for (int ks = 0; ks < 8; ks++) {
      bf16x8 afr = *(const bf16x8*)(qrow + ks * 32);
      if (n >= 8) afr = zz;  // qk rows 8..15 are zero (compact storage)
      bf16x8 bfr = *(const bf16x8*)(xrow + ks * 32);
      dacc = __builtin_amdgcn_mfma_f32_16x16x32_bf16(afr, bfr, dacc, 0, 0, 0);
    }
    // softmax over 8 slots for token tokbase+tt*16+n; C rows quad*4+r = slot
    float v[4], p[4];
    #pragma unroll
    for (int r = 0; r < 4; r++) v[r] = dacc[r] * 0.0625f;
    #pragma unroll
    for (int r = 0; r < 4; r++) p[r] = __shfl_xor(v[r], 16, 64);
    float mx = fmaxf(fmaxf(fmaxf(v[0], v[1]), fmaxf(v[2], v[3])),
                     fmaxf(fmaxf(p[0], p[1]), fmaxf(p[2], p[3])));
    float e[4], se = 0.f;
    #pragma unroll
    for (int r = 0; r < 4; r++) { e[r] = expf(v[r] - mx); se += e[r]; }
    float so = __shfl_xor(se, 16, 64);
    float inv = 1.f / (se + so);
    if (lane < 32) {
      float* ab = attn + (size_t)b * NSc * Nc + (size_t)(quad * 4) * Nc + (tokbase + tt * 16 + n);
      #pragma unroll
      for (int r = 0; r < 4; r++) {
        float a = e[r] * inv + EPSf;
        sacc[r] += a;
        ab[(size_t)r * Nc] = a;
        at_bf[w][quad * 4 + r][tt * 16 + n] = f2bfu(a);
      }
    }
  }
  // S partials (fp32): sum over the quad's 16 token-lanes
  if (lane < 32) {
    #pragma unroll
    for (int r = 0; r < 4; r++) {
      float s = sacc[r];
      s += __shfl_xor(s, 1, 64);
      s += __shfl_xor(s, 2, 64);
      s += __shfl_xor(s, 4, 64);
      s += __shfl_xor(s, 8, 64);
      if (n == 0) atomicAdd(&S[b * NSc + quad * 4 + r], s);
    }
  }
  // PV: A = at_bf rows (slot x tok), B = XT rows (d x tok); K = 128 toks
  bf16x8 afr[4];
  #pragma unroll
  for (int kk = 0; kk < 4; kk++)
    afr[kk] = *(const bf16x8*)&at_bf[w][n][kk * 32 + quad * 8];
  const unsigned short* xtb = XT + ((size_t)(b * 256 + n)) * 4096 + tokbase + quad * 8;
  #pragma unroll
  for (int nt = 0; nt < 16; nt++) {
    f32x4 pacc = {0.f, 0.f, 0.f, 0.f};
    const unsigned short* xr = xtb + (size_t)(nt * 16) * 4096;
    #pragma unroll
    for (int kk = 0; kk < 4; kk++) {
      bf16x8 bfr = *(const bf16x8*)(xr + kk * 32);
      pacc = __builtin_amdgcn_mfma_f32_16x16x32_bf16(afr[kk], bfr, pacc, 0, 0, 0);
    }
    if (lane < 32) {
      #pragma unroll
      for (int r = 0; r < 4; r++)
        updw[w][quad * 4 + r][nt * 16 + n] = pacc[r];
    }
  }
  __syncthreads();
  // block reduce over 4 waves, then 8 atomics per thread (8-way inter-block contention)
  for (int i = 0; i < 8; i++) {
    float s = updw[0][i][t] + updw[1][i][t] + updw[2][i][t] + updw[3][i][t];
    atomicAdd(&updraw[(size_t)(b * NSc + i) * 256 + t], s);
  }
}

// Relational MLP + Wv-transform of updates + X build. grid 64
__global__ __launch_bounds__(256) void k_slot_a(const float* __restrict__ slots,
                                                const float* __restrict__ updraw,
                                                const float* __restrict__ S,
                                                const unsigned short* __restrict__ Tw,
                                                const unsigned short* __restrict__ WvTb,
                                                const float* __restrict__ b1,
                                                const float* __restrict__ b2,
                                                unsigned short* __restrict__ Xb) {
  __shared__ float sp[NSc][256];
  __shared__ float un[4][256];
  __shared__ float xpart[2][12][128];
  __shared__ float xabl[12][128];
  __shared__ float hs[4][128];
  int t = threadIdx.x;
  int b = blockIdx.x >> 1, half = blockIdx.x & 1;
  int i0 = half * 4;
  for (int x = t; x < NSc * 256; x += 256) sp[x >> 8][x & 255] = slots[b * NSc * 256 + x];
  for (int r = 0; r < 4; r++) {
    int grow = b * NSc + i0 + r;
    un[r][t] = updraw[(size_t)grow * 256 + t] / S[grow];
  }
  __syncthreads();
  {
    float av[4] = {0.f, 0.f, 0.f, 0.f};
    for (int d = 0; d < 256; d++) {
      float wv = bf2f(WvTb[d * 256 + t]);
      #pragma unroll
      for (int r = 0; r < 4; r++) av[r] += wv * un[r][d];
    }
    for (int r = 0; r < 4; r++) {
      int grow = b * NSc + i0 + r;
      Xb[(size_t)grow * 768 + t] = f2bfu(av[r]);
      Xb[(size_t)grow * 768 + 512 + t] = f2bfu(sp[i0 + r][t]);
    }
  }
  int h = t & 127, dh = t >> 7;
  {
    const unsigned short* wa = Tw + W1AT;
    const unsigned short* wb = Tw + W1BT;
    float accb[8] = {0, 0, 0, 0, 0, 0, 0, 0};
    float acca[4] = {0, 0, 0, 0};
    for (int dd = 0; dd < 128; dd++) {
      int d = dh * 128 + dd;
      float wbv = bf2f(wb[d * 128 + h]);
      float wav = bf2f(wa[d * 128 + h]);
      #pragma unroll
      for (int jj = 0; jj < 8; jj++) accb[jj] += wbv * sp[jj][d];
      #pragma unroll
      for (int r = 0; r < 4; r++) acca[r] += wav * sp[i0 + r][d];
    }
    #pragma unroll
    for (int jj = 0; jj < 8; jj++) xpart[dh][jj][h] = accb[jj];
    #pragma unroll
    for (int r = 0; r < 4; r++) xpart[dh][8 + r][h] = acca[r];
  }
  __syncthreads();
  {
    int g = t >> 7;
    for (int jj = g * 6; jj < g * 6 + 6; jj++)
      xabl[jj][h] = xpart[0][jj][h] + xpart[1][jj][h];
  }
  __syncthreads();
  {
    float bv = b1[h];
    int ig = t >> 7;
    #pragma unroll
    for (int ii = 0; ii < 2; ii++) {
      int il = ig * 2 + ii;
      int ibatch = i0 + il;
      float av = xabl[8 + il][h];
      float s = 0.f;
      #pragma unroll
      for (int jj = 0; jj < NSc; jj++) {
        if (jj == ibatch) continue;
        s += fmaxf(av + xabl[jj][h] + bv, 0.f);
      }
      hs[il][h] = s;
    }
  }
  __syncthreads();
  {
    const unsigned short* w2 = Tw + W2T;
    float am[4] = {0, 0, 0, 0};
    for (int hh = 0; hh < 128; hh++) {
      float wv = bf2f(w2[hh * 256 + t]);
      #pragma unroll
      for (int r = 0; r < 4; r++) am[r] += wv * hs[r][hh];
    }
    float bv2 = b2[t];
    for (int r = 0; r < 4; r++) {
      float rel = am[r] * (1.0f / 7.0f) + bv2;
      Xb[(size_t)(b * NSc + i0 + r) * 768 + 256 + t] = f2bfu(rel);
    }
  }
}

// Gates GEMM: Y[256][768]; n-tiles 0..7 use Wcat1 (K=768), 8..11 use Wcat2 (K=512). grid 48
__global__ __launch_bounds__(256) void k_gates(const unsigned short* __restrict__ Xb,
                                               const unsigned short* __restrict__ Wcat1,
                                               const unsigned short* __restrict__ Wcat2,
                                               unsigned short* __restrict__ Yb) {
  __shared__ unsigned short Als[64 * 64];
  __shared__ unsigned short Bls[64 * 64];
  int tid = threadIdx.x;
  int lane = tid & 63, w = tid >> 6;
  int idx16 = lane & 15, quad = lane >> 4;
  int mt6 = blockIdx.x / 12, ntile = blockIdx.x % 12;
  int m0 = mt6 * 64;
  int n0 = ntile * 64;
  const unsigned short* wb;
  int ktm;
  size_t rowbytes;
  if (ntile < 8) { wb = Wcat1 + (size_t)n0 * 768; ktm = 12; rowbytes = 1536; }
  else { wb = Wcat2 + (size_t)(ntile - 8) * 64 * 512; ktm = 8; rowbytes = 1024; }
  int wm = w & 1, wn = w >> 1;
  f32x4 acc[2][2];
  #pragma unroll
  for (int i = 0; i < 2; i++)
    #pragma unroll
    for (int j = 0; j < 2; j++) acc[i][j] = (f32x4){0.f, 0.f, 0.f, 0.f};

  for (int kt = 0; kt < ktm; kt++) {
    int k0 = kt * 64;
    #pragma unroll
    for (int c = 0; c < 2; c++) {
      int idx = (w * 2 + c) * 64 + lane;
      int row = idx >> 3, lc = idx & 7;
      int gc = lc ^ (row & 7);
      gl_lds16((const char*)Xb + (size_t)(m0 + row) * 1536 + k0 * 2 + gc * 16,
               (char*)Als + (size_t)(w * 2 + c) * 1024);
      gl_lds16((const char*)wb + (size_t)row * rowbytes + k0 * 2 + gc * 16,
               (char*)Bls + (size_t)(w * 2 + c) * 1024);
    }
    __syncthreads();
    #pragma unroll
    for (int ks = 0; ks < 2; ks++) {
      bf16x8 af[2], bfr[2];
      int kchunk = ks * 4 + quad;
      #pragma unroll
      for (int mt = 0; mt < 2; mt++) {
        int row = wm * 32 + mt * 16 + idx16;
        af[mt] = *(const bf16x8*)((const char*)Als + (size_t)(row * 8 + (kchunk ^ (row & 7))) * 16);
      }
      #pragma unroll
      for (int nt = 0; nt < 2; nt++) {
        int row = wn * 32 + nt * 16 + idx16;
        bfr[nt] = *(const bf16x8*)((const char*)Bls + (size_t)(row * 8 + (kchunk ^ (row & 7))) * 16);
      }
      #pragma unroll
      for (int mt = 0; mt < 2; mt++)
        #pragma unroll
        for (int nt = 0; nt < 2; nt++)
          acc[mt][nt] = __builtin_amdgcn_mfma_f32_16x16x32_bf16(af[mt], bfr[nt], acc[mt][nt], 0, 0, 0);
    }
    __syncthreads();
  }
  #pragma unroll
  for (int mt = 0; mt < 2; mt++) {
    #pragma unroll
    for (int nt = 0; nt < 2; nt++) {
      int gm = m0 + wm * 32 + mt * 16 + quad * 4;
      int col = n0 + wn * 32 + nt * 16 + idx16;
      #pragma unroll
      for (int r = 0; r < 4; r++)
        Yb[(size_t)(gm + r) * 768 + col] = f2bfu(acc[mt][nt][r]);
    }
  }
}

// GRU elementwise + LN + FF + residual + next-iter qk. grid 64 (4 rows/block)
__global__ __launch_bounds__(256) void k_slot_c(const unsigned short* __restrict__ Yb,
                                                const unsigned short* __restrict__ Tw,
                                                const unsigned short* __restrict__ MTb,
                                                const float* __restrict__ b_ih,
                                                const float* __restrict__ b_hh,
                                                float* __restrict__ slots,
                                                const float* __restrict__ ob1,
                                                const float* __restrict__ ob2,
                                                const float* __restrict__ lng,
                                                const float* __restrict__ lnb,
                                                const float* __restrict__ lsg,
                                                const float* __restrict__ lsb,
                                                unsigned short* __restrict__ qkb,
                                                float* __restrict__ updraw,
                                                float* __restrict__ S,
                                                float* __restrict__ outf,
                                                int wfinal) {
  __shared__ float sp4[4][256];
  __shared__ float ffl[4][256];
  __shared__ float h1p[2][4][128];
  __shared__ float h1l[4][128];
  __shared__ float xs2[4][256];
  int t = threadIdx.x;
  int g0 = blockIdx.x * 4;
  for (int x = t; x < 1024; x += 256) sp4[x >> 8][x & 255] = slots[(size_t)g0 * 256 + x];
  __syncthreads();
  float hn[4] = {0, 0, 0, 0};
  {
    const unsigned short* wh = Tw + WHNT;
    for (int d = 0; d < 256; d++) {
      float wv = bf2f(wh[d * 256 + t]);
      #pragma unroll
      for (int r = 0; r < 4; r++) hn[r] += wv * sp4[r][d];
    }
  }
  float bir = b_ih[t], bhr = b_hh[t];
  float biz = b_ih[256 + t], bhz = b_hh[256 + t];
  float bin_ = b_ih[512 + t], bhn = b_hh[512 + t];
  float snew[4];
  #pragma unroll
  for (int r = 0; r < 4; r++) {
    size_t yoff = (size_t)(g0 + r) * 768;
    float yr = bf2f((unsigned int)Yb[yoff + t]);
    float yz = bf2f((unsigned int)Yb[yoff + 256 + t]);
    float yx = bf2f((unsigned int)Yb[yoff + 512 + t]);
    float rg = sigmf(yr + bir + bhr);
    float zg = sigmf(yz + biz + bhz);
    float ng = tanhf(yx + bin_ + rg * (hn[r] + bhn));
    snew[r] = (1.f - zg) * ng + zg * sp4[r][t];
    ffl[r][t] = snew[r];
  }
  __syncthreads();
  {
    int wv = t >> 6, lane = t & 63;
    float4 v = *(const float4*)&ffl[wv][lane * 4];
    float s = v.x + v.y + v.z + v.w;
    float q = v.x * v.x + v.y * v.y + v.z * v.z + v.w * v.w;
    #pragma unroll
    for (int o = 32; o > 0; o >>= 1) { s += __shfl_down(s, o, 64); q += __shfl_down(q, o, 64); }
    s = __shfl(s, 0, 64); q = __shfl(q, 0, 64);
    float mu = s * (1.0f / 256.0f);
    float rs = rsqrtf(q * (1.0f / 256.0f) - mu * mu + LN_EPSf);
    float4 g4 = *(const float4*)&lng[lane * 4];
    float4 b4 = *(const float4*)&lnb[lane * 4];
    float4 o4;
    o4.x = (v.x - mu) * rs * g4.x + b4.x;
    o4.y = (v.y - mu) * rs * g4.y + b4.y;
    o4.z = (v.z - mu) * rs * g4.z + b4.z;
    o4.w = (v.w - mu) * rs * g4.w + b4.w;
    *(float4*)&ffl[wv][lane * 4] = o4;
  }
  __syncthreads();
  {
    const unsigned short* w1 = Tw + OW1T;
    int h = t & 127, dh = t >> 7;
    float a1[4] = {0, 0, 0, 0};
    for (int dd = 0; dd < 128; dd++) {
      int d = dh * 128 + dd;
      float wv = bf2f(w1[d * 128 + h]);
      #pragma unroll
      for (int r = 0; r < 4; r++) a1[r] += wv * ffl[r][d];
    }
    #pragma unroll
    for (int r = 0; r < 4; r++) h1p[dh][r][h] = a1[r];
  }
  __syncthreads();
  {
    int h = t & 127, g = t >> 7;
    float bo = ob1[h];
    #pragma unroll
    for (int rr = 0; rr < 2; rr++) {
      int r = g * 2 + rr;
      h1l[r][h] = fmaxf(h1p[0][r][h] + h1p[1][r][h] + bo, 0.f);
    }
  }
  __syncthreads();
  float res[4];
  {
    const unsigned short* w2 = Tw + OW2T;
    float ao[4] = {0, 0, 0, 0};
    for (int hh = 0; hh < 128; hh++) {
      float wv = bf2f(w2[hh * 256 + t]);
      #pragma unroll
      for (int r = 0; r < 4; r++) ao[r] += wv * h1l[r][hh];
    }
    float bo2 = ob2[t];
    #pragma unroll
    for (int r = 0; r < 4; r++) res[r] = snew[r] + ao[r] + bo2;
  }
  #pragma unroll
  for (int r = 0; r < 4; r++) {
    slots[(size_t)(g0 + r) * 256 + t] = res[r];
    if (wfinal) outf[(size_t)(g0 + r) * 256 + t] = res[r];
    xs2[r][t] = res[r];
  }
  __syncthreads();
  {
    int wv = t >> 6, lane = t & 63;
    float4 v = *(const float4*)&xs2[wv][lane * 4];
    float s = v.x + v.y + v.z + v.w;
    float q = v.x * v.x + v.y * v.y + v.z * v.z + v.w * v.w;
    #pragma unroll
    for (int o = 32; o > 0; o >>= 1) { s += __shfl_down(s, o, 64); q += __shfl_down(q, o, 64); }
    s = __shfl(s, 0, 64); q = __shfl(q, 0, 64);
    float mu = s * (1.0f / 256.0f);
    float rs = rsqrtf(q * (1.0f / 256.0f) - mu * mu + LN_EPSf);
    float4 g4 = *(const float4*)&lsg[lane * 4];
    float4 b4 = *(const float4*)&lsb[lane * 4];
    float4 o4;
    o4.x = (v.x - mu) * rs * g4.x + b4.x;
    o4.y = (v.y - mu) * rs * g4.y + b4.y;
    o4.z = (v.z - mu) * rs * g4.z + b4.z;
    o4.w = (v.w - mu) * rs * g4.w + b4.w;
    *(float4*)&xs2[wv][lane * 4] = o4;
  }
  __syncthreads();
  {
    float aq[4] = {0, 0, 0, 0};
    for (int d = 0; d < 256; d++) {
      float wv = bf2f(MTb[d * 256 + t]);
      #pragma unroll
      for (int r = 0; r < 4; r++) aq[r] += wv * xs2[r][d];
    }
    #pragma unroll
    for (int r = 0; r < 4; r++)
      qkb[(size_t)(g0 + r) * 256 + t] = f2bfu(aq[r]);
  }
  #pragma unroll
  for (int r = 0; r < 4; r++) updraw[(size_t)(g0 + r) * 256 + t] = 0.f;
  if (t < 4) S[g0 + t] = 0.f;
}

extern "C" void kernel_launch(void* const* d_in, const int* in_sizes, int n_in,
                              void* d_out, int out_size, void* d_ws, size_t ws_size,
                              hipStream_t stream) {
  const float* inputs      = (const float*)d_in[0];
  const float* slot_noise  = (const float*)d_in[1];
  const float* slots_mu    = (const float*)d_in[2];
  const float* slots_sigma = (const float*)d_in[3];
  const float* Wq          = (const float*)d_in[4];
  const float* Wk          = (const float*)d_in[5];
  const float* Wv          = (const float*)d_in[6];
  const float* gru_w_ih    = (const float*)d_in[7];
  const float* gru_w_hh    = (const float*)d_in[8];
  const float* gru_b_ih    = (const float*)d_in[9];
  const float* gru_b_hh    = (const float*)d_in[10];
  const float* obj_w1      = (const float*)d_in[11];
  const float* obj_b1      = (const float*)d_in[12];
  const float* obj_w2      = (const float*)d_in[13];
  const float* obj_b2      = (const float*)d_in[14];
  const float* rel_w1      = (const float*)d_in[15];
  const float* rel_b1      = (const float*)d_in[16];
  const float* rel_w2      = (const float*)d_in[17];
  const float* rel_b2      = (const float*)d_in[18];
  const float* ln_in_g     = (const float*)d_in[19];
  const float* ln_in_b     = (const float*)d_in[20];
  const float* ln_s_g      = (const float*)d_in[21];
  const float* ln_s_b      = (const float*)d_in[22];
  const float* ln_ff_g     = (const float*)d_in[23];
  const float* ln_ff_b     = (const float*)d_in[24];

  // workspace layout (bytes), total 137,298,944 <= proven 137,364,480:
  //   X bf16    : 0           (+67,108,864)
  //   XT bf16   : 67,108,864  (+67,108,864)
  //   slots f32 : 134,217,728 (+262,144)
  //   updraw f32: 134,479,872 (+262,144)
  //   Sbuf f32  : 134,742,016 (+1,024)
  //   Wcat1 bf16: 134,743,040 (+786,432)
  //   Wcat2 bf16: 135,529,472 (+262,144)
  //   Tw bf16   : 135,791,616 (+458,752)
  //   MTb bf16  : 136,250,368 (+131,072)
  //   WvTb bf16 : 136,381,440 (+131,072)
  //   Xbuf bf16 : 136,512,512 (+393,216)  [qkb (131,072) aliases head: attn reads qkb
  //                                        before slot_a rewrites Xbuf; slot_c writes
  //                                        qkb after gates consumed Xbuf]
  //   Ybuf bf16 : 136,905,728 (+393,216)
  char* w = (char*)d_ws;
  unsigned short* X  = (unsigned short*)(w);
  unsigned short* XT = (unsigned short*)(w + (size_t)67108864);
  float* slots  = (float*)(w + (size_t)134217728);
  float* updraw = (float*)(w + (size_t)134479872);
  float* Sbuf   = (float*)(w + (size_t)134742016);
  unsigned short* Wcat1 = (unsigned short*)(w + (size_t)134743040);
  unsigned short* Wcat2 = (unsigned short*)(w + (size_t)135529472);
  unsigned short* Tw    = (unsigned short*)(w + (size_t)135791616);
  unsigned short* MTb   = (unsigned short*)(w + (size_t)136250368);
  unsigned short* WvTb  = (unsigned short*)(w + (size_t)136381440);
  unsigned short* Xbuf  = (unsigned short*)(w + (size_t)136512512);
  unsigned short* qkb   = (unsigned short*)(w + (size_t)136512512);
  unsigned short* Ybuf  = (unsigned short*)(w + (size_t)136905728);

  float* out = (float*)d_out;
  float* attn_base = out + (size_t)Bc * NSc * Dc;

  k_init_slots<<<Bc * NSc * Dc / 256, 256, 0, stream>>>(slot_noise, slots_mu, slots_sigma, slots);
  k_lnx<<<Bc * 64, 256, 0, stream>>>(inputs, ln_in_g, ln_in_b, X, XT);
  k_wprep<<<(512 * 768 + 256 * 512) / 256, 256, 0, stream>>>(gru_w_ih, gru_w_hh, Wcat1, Wcat2);
  k_tprep<<<(TW_ELEMS + 255) / 256, 256, 0, stream>>>(rel_w1, rel_w2, obj_w1, obj_w2, gru_w_hh, Tw);
  k_mprep<<<256, 256, 0, stream>>>(Wk, Wq, Wv, MTb, WvTb);
  k_qproj0<<<Bc * NSc, 256, 0, stream>>>(slots, MTb, ln_s_g, ln_s_b, qkb, Sbuf, updraw);

  for (int it = 0; it < ITERSc; it++) {
    float* attn = attn_base + (size_t)it * Bc * NSc * Nc;
    k_attn<<<Bc * 8, 256, 0, stream>>>(qkb, X, XT, attn, Sbuf, updraw);
    k_slot_a<<<Bc * 2, 256, 0, stream>>>(slots, updraw, Sbuf, Tw, WvTb, rel_b1, rel_b2, Xbuf);
    k_gates<<<4 * 12, 256, 0, stream>>>(Xbuf, Wcat1, Wcat2, Ybuf);
    k_slot_c<<<64, 256, 0, stream>>>(Ybuf, Tw, MTb, gru_b_ih, gru_b_hh, slots,
                                     obj_b1, obj_b2, ln_ff_g, ln_ff_b, ln_s_g, ln_s_b,
                                     qkb, updraw, Sbuf,
                                     out, it == ITERSc - 1 ? 1 : 0);
  }
}